// Round 1
// baseline (182.004 us; speedup 1.0000x reference)
//
#include <hip/hip_runtime.h>
#include <hip/hip_bf16.h>
#include <stdint.h>

#define L1DIM 1536
#define NOUT  144           // 128 (W1) + 16 (Wf) layer-1 outputs
#define MTILE 16            // rows per block
#define BK    128           // K per staged slab (4 MFMA k-steps, one per wave)
#define NITER (L1DIM / BK)  // 12

typedef __bf16 bf16;
typedef __bf16 bf16x8 __attribute__((ext_vector_type(8)));
typedef float  floatx4 __attribute__((ext_vector_type(4)));

// ---------------------------------------------------------------------------
// Pack [W1;Wf] (144 x 1536 fp32) -> bf16 in MFMA B-fragment order:
//   pw[(k/8)*144 + n][0..7]  (16 B per (k-octet, feature)).
// Unchanged from previous version.
// ---------------------------------------------------------------------------
__global__ void pack_weights(const float* __restrict__ W1,
                             const float* __restrict__ Wf,
                             bf16* __restrict__ pw) {
    int t = blockIdx.x * blockDim.x + threadIdx.x;   // 0 .. 144*192-1
    if (t >= NOUT * 192) return;
    int n = t / 192;         // output feature 0..143
    int o = t % 192;         // k-octet 0..191
    const float* src = (n < 128) ? (W1 + (size_t)n * L1DIM + o * 8)
                                 : (Wf + (size_t)(n - 128) * L1DIM + o * 8);
    float4 s0 = ((const float4*)src)[0];
    float4 s1 = ((const float4*)src)[1];
    bf16x8 v;
    v[0] = (bf16)s0.x; v[1] = (bf16)s0.y; v[2] = (bf16)s0.z; v[3] = (bf16)s0.w;
    v[4] = (bf16)s1.x; v[5] = (bf16)s1.y; v[6] = (bf16)s1.z; v[7] = (bf16)s1.w;
    *(bf16x8*)(pw + ((size_t)o * NOUT + n) * 8) = v;
}

__device__ __forceinline__ void gload_lds16(const void* g, void* l) {
    __builtin_amdgcn_global_load_lds(
        (const __attribute__((address_space(1))) void*)g,
        (__attribute__((address_space(3))) void*)l, 16, 0, 0);
}

__device__ __forceinline__ bf16x8 cvt8(float4 a, float4 b) {
    bf16x8 r;
    r[0] = (bf16)a.x; r[1] = (bf16)a.y; r[2] = (bf16)a.z; r[3] = (bf16)a.w;
    r[4] = (bf16)b.x; r[5] = (bf16)b.y; r[6] = (bf16)b.z; r[7] = (bf16)b.w;
    return r;
}

// ---------------------------------------------------------------------------
// Restructured for latency hiding:
//  - MTILE=16 rows/block, grid 1024 = 4 blocks/CU (16 waves/CU vs previous 8).
//  - 4 waves = 4-way K-split: wave ks owns k-range [ks*32, ks*32+32) of each
//    BK=128 slab, computes ALL 9 n-tiles (9 accumulators); partials summed
//    via ep4[4][16][33] in LDS at the end.
//  - B fragments are loaded DIRECTLY from pw (global, fragment-ordered,
//    L2-resident) -- no LDS staging for B, so the per-iter barrier drains
//    only the 8 KB A slab, and LDS/block drops to 24.8 KB.
//  - A staged via global_load_lds width-16, double-buffered, XOR-swizzled
//    (chunk ^ (row&7)) folded into the global fetch address as before.
// ---------------------------------------------------------------------------
__global__ __launch_bounds__(256, 4) void layerstacks_main(
    const float* __restrict__ x, const int* __restrict__ lsidx,
    const bf16* __restrict__ pw,
    const float* __restrict__ b1, const float* __restrict__ bf_,
    const float* __restrict__ W2, const float* __restrict__ b2,
    const float* __restrict__ Wo, const float* __restrict__ bo,
    float* __restrict__ out)
{
    __shared__ float la[2][MTILE * BK];   // 2 x 8192 B   (A, fp32, swizzled)
    __shared__ float ep4[4][MTILE][33];   // 8448 B       (per-wave partials)

    const int tid  = threadIdx.x;
    const int wv   = tid >> 6;            // wave id == ks (k-quarter)
    const int ln   = tid & 63;
    const int quad = ln >> 4;
    const int lm   = ln & 15;
    const int ks   = wv;

    const int R0 = blockIdx.x * MTILE;

    // ---- A staging lane geometry (fixed per lane) ----
    // instr j covers rows 2j, 2j+1 (each row = 128 floats = 32 chunks of 16B).
    // lane i -> row 2j + (i>>5), lds slot i&31, global chunk (i&31)^(row&7).
    const int sro = ln >> 5;              // row-within-pair 0..1
    const int sch = ln & 31;              // lds slot 0..31

    floatx4 acc[9];
#pragma unroll
    for (int i = 0; i < 9; i++) acc[i] = (floatx4){0.f, 0.f, 0.f, 0.f};

#define STAGE(buf, ki_)                                                        \
    {                                                                          \
        const int k0_ = (ki_) * BK;                                            \
        _Pragma("unroll")                                                      \
        for (int jj = 0; jj < 2; jj++) {                                       \
            const int j   = 2 * wv + jj;                                       \
            const int row = 2 * j + sro;                                       \
            const int cg  = sch ^ (row & 7);                                   \
            gload_lds16(x + (size_t)(R0 + row) * L1DIM + k0_ + cg * 4,         \
                        &la[buf][j * 2 * BK + sro * BK + sch * 4]);            \
        }                                                                      \
    }

    STAGE(0, 0)
    __syncthreads();

    const int c0 = ks * 8 + quad * 2;     // 16B-chunk index of this lane's k

    for (int ki = 0; ki < NITER; ki++) {
        const int cur = ki & 1;
        if (ki < NITER - 1) STAGE(cur ^ 1, ki + 1)

        // A-frag: row = lm, k = ks*32 + quad*8 .. +7 (chunks c0, c0+1)
        const int row = lm;
        float4 a0 = *(const float4*)&la[cur][row * BK + ((c0)     ^ (row & 7)) * 4];
        float4 a1 = *(const float4*)&la[cur][row * BK + ((c0 + 1) ^ (row & 7)) * 4];
        bf16x8 af = cvt8(a0, a1);

        // B-frags straight from global (fragment-ordered, L2-resident):
        // octet = ki*16 + ks*4 + quad; lane lm walks 16 consecutive features.
        const bf16* bsl = pw + ((size_t)(ki * 16 + ks * 4 + quad) * NOUT) * 8;
#pragma unroll
        for (int t = 0; t < 9; t++) {
            bf16x8 bfrag = *(const bf16x8*)(bsl + ((size_t)(t * 16 + lm)) * 8);
            acc[t] = __builtin_amdgcn_mfma_f32_16x16x32_bf16(af, bfrag, acc[t], 0, 0, 0);
        }
        __syncthreads();   // drains next-slab A staging; frees cur for overwrite
    }

    // ---- per-wave bucket-gather into ep4[ks] ----
    // C layout: row = quad*4 + r, col = lm. tile t covers features [16t,16t+16):
    // buckets 0..7 == tiles 0..7, Wf == tile 8.
    {
#pragma unroll
        for (int r = 0; r < 4; r++) {
            const int row = quad * 4 + r;
            const int bkt = lsidx[R0 + row];
            float c = acc[0][r];
#pragma unroll
            for (int t = 1; t < 8; t++) c = (bkt == t) ? acc[t][r] : c;
            ep4[ks][row][lm]      = c;          // selected-bucket col
            ep4[ks][row][16 + lm] = acc[8][r];  // shared (Wf) col
        }
    }
    __syncthreads();

    // ---- reduce the 4 k-quarter partials into ep4[0] ----
    {
        const int col = tid & 31;
        const int rr  = tid >> 5;             // 0..7
#pragma unroll
        for (int p = 0; p < 2; p++) {
            const int row = rr + p * 8;
            ep4[0][row][col] = ep4[0][row][col] + ep4[1][row][col]
                             + ep4[2][row][col] + ep4[3][row][col];
        }
    }
    __syncthreads();

    // ---- epilogue: 8 threads per row, 16 rows (threads 0..127) ----
    if (tid < 128) {
        const int er   = tid >> 3;        // row in tile, 0..15
        const int sub  = tid & 7;         // output-group, 0..7
        const int grow = R0 + er;
        const int bkt  = lsidx[grow];

        const float l1c15 = ep4[0][er][15] + b1[bkt * 16 + 15];
        const float l1f15 = ep4[0][er][31] + bf_[15];

        float l1x[30];
#pragma unroll
        for (int j = 0; j < 15; j++) {
            float tj = (ep4[0][er][j] + b1[bkt * 16 + j]) + (ep4[0][er][16 + j] + bf_[j]);
            float sq = tj * tj * (127.0f / 128.0f);
            l1x[j]      = fminf(fmaxf(sq, 0.f), 1.f);
            l1x[15 + j] = fminf(fmaxf(tj, 0.f), 1.f);
        }

        float part = 0.f;
#pragma unroll
        for (int o = 0; o < 8; o++) {
            const int oi = bkt * 64 + sub * 8 + o;
            const float2* wrow = (const float2*)(W2 + oi * 30);   // 8B-aligned
            float a = b2[oi];
#pragma unroll
            for (int j2 = 0; j2 < 15; j2++) {
                float2 w = wrow[j2];
                a += l1x[2 * j2] * w.x + l1x[2 * j2 + 1] * w.y;
            }
            a = fminf(fmaxf(a, 0.f), 1.f);
            part += a * Wo[oi];
        }
        part += __shfl_xor(part, 1);
        part += __shfl_xor(part, 2);
        part += __shfl_xor(part, 4);
        if (sub == 0) out[grow] = part + bo[bkt] + l1c15 + l1f15;
    }
}

extern "C" void kernel_launch(void* const* d_in, const int* in_sizes, int n_in,
                              void* d_out, int out_size, void* d_ws, size_t ws_size,
                              hipStream_t stream) {
    const float* x   = (const float*)d_in[0];
    const int*   idx = (const int*)  d_in[1];
    const float* W1  = (const float*)d_in[2];
    const float* b1  = (const float*)d_in[3];
    const float* Wf  = (const float*)d_in[4];
    const float* bf  = (const float*)d_in[5];
    const float* W2  = (const float*)d_in[6];
    const float* b2  = (const float*)d_in[7];
    const float* Wo  = (const float*)d_in[8];
    const float* bo  = (const float*)d_in[9];
    float* out = (float*)d_out;
    bf16*  pw  = (bf16*)d_ws;                 // 442368 B of workspace

    pack_weights<<<dim3((NOUT * 192 + 255) / 256), dim3(256), 0, stream>>>(W1, Wf, pw);
    layerstacks_main<<<dim3(16384 / MTILE), dim3(256), 0, stream>>>(
        x, idx, pw, b1, bf, W2, b2, Wo, bo, out);
}